// Round 5
// baseline (256.161 us; speedup 1.0000x reference)
//
#include <hip/hip_runtime.h>
#include <hip/hip_fp16.h>

#define N_NODES 100000
#define N_EDGES 3200000
#define F_IN    128
#define F_HID   32

#define BSHIFT  7
#define BKSZ    128                               // nodes per bucket
#define NBKT    ((N_NODES + BKSZ - 1) / BKSZ)     // 782
#define CAP     4608                              // bucket capacity: mean 4092 + 8 sigma (div by 4)
#define CHUNK   4096                              // edges per partition block
#define NBLK_E  ((N_EDGES + CHUNK - 1) / CHUNK)   // 782
#define RBITS   17                                // row id bits (100000 < 2^17)
#define RMASK   0x1FFFF

// fast tanh: 1 - 2/(exp2(x*2/ln2)+1). v_exp_f32 + v_rcp_f32 are ~1ulp approx
// -> abs err ~1e-6, far under the fp16-storage error budget (absmax ~1e-3).
__device__ __forceinline__ float fast_tanh(float x) {
    float t = __builtin_amdgcn_exp2f(x * 2.88539008f);   // e^{2x}
    return 1.0f - 2.0f * __builtin_amdgcn_rcpf(t + 1.0f);
}

// ---------------- coarse partition (fixed-capacity buckets, relative cursors) ----------------
// gcur[] zeroed by hipMemsetAsync; holds per-bucket edge count after k_part.

__global__ __launch_bounds__(512) void k_part(const int* __restrict__ row, const int* __restrict__ col,
                                              int* __restrict__ gcur, unsigned* __restrict__ bkt) {
    __shared__ int hist[NBKT];
    __shared__ int lbase[NBKT];          // local (block) exclusive prefix
    __shared__ int gbase[NBKT];          // global destination base (absolute)
    __shared__ unsigned perm[CHUNK];     // 16 KB: packed words, bucket-major
    __shared__ unsigned short pb[CHUNK]; // 8 KB: bucket id per slot
    __shared__ int wt[8];
    int t = threadIdx.x;
    for (int i = t; i < NBKT; i += 512) hist[i] = 0;
    __syncthreads();

    int e0 = blockIdx.x * CHUNK;
    int n  = min(CHUNK, N_EDGES - e0);
    int r[8], c[8], rk[8];
#pragma unroll
    for (int k = 0; k < 8; k++) {
        int idx = t + k * 512;
        if (idx < n) {
            r[k]  = row[e0 + idx];
            c[k]  = col[e0 + idx];
            rk[k] = atomicAdd(&hist[c[k] >> BSHIFT], 1);   // local rank in bucket
        }
    }
    __syncthreads();

    // block scan: each thread owns 2 consecutive buckets
    {
        int b0 = t * 2;
        int s0 = (b0     < NBKT) ? hist[b0]     : 0;
        int s1 = (b0 + 1 < NBKT) ? hist[b0 + 1] : 0;
        int tsum = s0 + s1;
        int lane = t & 63, wid = t >> 6;
        int incl = tsum;
#pragma unroll
        for (int sh = 1; sh < 64; sh <<= 1) {
            int u = __shfl_up(incl, sh);
            if (lane >= sh) incl += u;
        }
        if (lane == 63) wt[wid] = incl;
        __syncthreads();
        int wpre = 0;
        for (int w = 0; w < wid; w++) wpre += wt[w];
        int excl = wpre + incl - tsum;
        if (b0     < NBKT) lbase[b0]     = excl;
        if (b0 + 1 < NBKT) lbase[b0 + 1] = excl + s0;
    }
    for (int i = t; i < NBKT; i += 512) {
        int h = hist[i];
        gbase[i] = i * CAP + (h ? atomicAdd(&gcur[i], h) : 0);
    }
    __syncthreads();

#pragma unroll
    for (int k = 0; k < 8; k++) {
        int idx = t + k * 512;
        if (idx < n) {
            int b   = c[k] >> BSHIFT;
            int pos = lbase[b] + rk[k];
            perm[pos] = (unsigned)r[k] | ((unsigned)(c[k] & (BKSZ - 1)) << RBITS);
            pb[pos]   = (unsigned short)b;
        }
    }
    __syncthreads();

    for (int i = t; i < n; i += 512) {
        int b = pb[i];
        bkt[gbase[b] + (i - lbase[b])] = perm[i];
    }
}

// ---------------- per-bucket fine sort, IN PLACE (LDS staging), + off/end/dinv ----------------

__global__ __launch_bounds__(1024) void k_bucket(unsigned* __restrict__ bkt,  // in: bkt, out: srt (aliased)
                                                 const int* __restrict__ gcur,
                                                 int* __restrict__ off, int* __restrict__ end,
                                                 float* __restrict__ dinv) {
    __shared__ unsigned stg[CAP];   // 18.4 KB staging
    __shared__ int cnt[BKSZ];
    __shared__ int cur[BKSZ];
    __shared__ int wtot[2];
    int t = threadIdx.x, b = blockIdx.x;
    int s = b * CAP, m = gcur[b];   // gcur holds the bucket count
    if (t < BKSZ) cnt[t] = 0;
    __syncthreads();
    for (int i = t; i < m; i += 1024) {
        unsigned x = bkt[s + i];
        stg[i] = x;
        atomicAdd(&cnt[x >> RBITS], 1);
    }
    __syncthreads();

    int lane = t & 63, wid = t >> 6;
    int v = 0, incl = 0;
    if (t < BKSZ) {
        v = cnt[t];
        incl = v;
        #pragma unroll
        for (int sh = 1; sh < 64; sh <<= 1) {
            int u = __shfl_up(incl, sh);
            if (lane >= sh) incl += u;
        }
        if (lane == 63) wtot[wid] = incl;
    }
    __syncthreads();
    if (t < BKSZ) {
        int wpre = (wid == 1) ? wtot[0] : 0;
        int excl = wpre + incl - v;
        cur[t] = s + excl;
        int g = b * BKSZ + t;
        if (g < N_NODES) {
            off[g]  = s + excl;
            end[g]  = s + excl + v;
            dinv[g] = rsqrtf((float)(v + 1));   // +1 self-loop
        }
    }
    __syncthreads();
    for (int i = t; i < m; i += 1024) {
        unsigned x = stg[i];
        int p = atomicAdd(&cur[x >> RBITS], 1);
        bkt[p] = x & RMASK;   // srt: row ids grouped by dest node
    }
}

// ---------------- gemm1 R16: 2-row x 4-feat register tile ----------------
// h1s = fp16( dinv[r] * (x @ W1)[r] ). R15 lesson: 4-row tile -> 781 blocks + VGPR 148
// -> 7.8% occupancy, latency-bound (55 us). 2-row keeps the W-read amortization (2x fewer
// LDS instrs than 1-row) at 1563 blocks (~6/CU) and ~8 accumulators -> VGPR well under 85.
// Row N_NODES is an all-zero row (gather target for predicated-off edges in k_conv1).

#define NGRP2 (N_NODES / 2)   // 50000 row pairs, exact

__global__ __launch_bounds__(256) void k_gemm1(const float* __restrict__ x, const float* __restrict__ W1,
                                               const float* __restrict__ dinv, unsigned* __restrict__ h1s) {
    __shared__ float Wlds[F_IN * F_HID];  // 16 KB, [k][f]
    int t = threadIdx.x;
    for (int i = t; i < F_IN * F_HID; i += 256) Wlds[i] = W1[i];
    __syncthreads();

    int gid = blockIdx.x * 256 + t;   // gid = g*8 + f4
    if (gid < 8) ((uint2*)h1s)[(size_t)N_NODES * 8 + gid] = make_uint2(0u, 0u);  // zero row
    int g = gid >> 3, f4 = gid & 7;
    if (g >= NGRP2) return;

    const float4* x4  = (const float4*)(x + (size_t)(2 * g) * F_IN);  // row stride = 32 float4
    const float4* Wl4 = (const float4*)Wlds;   // [(k)*8 + f4]

    float a0x = 0.f, a0y = 0.f, a0z = 0.f, a0w = 0.f;
    float a1x = 0.f, a1y = 0.f, a1z = 0.f, a1w = 0.f;

#pragma unroll
    for (int k4 = 0; k4 < F_IN / 4; k4++) {
        float4 w0 = Wl4[(4 * k4 + 0) * 8 + f4];
        float4 w1 = Wl4[(4 * k4 + 1) * 8 + f4];
        float4 w2 = Wl4[(4 * k4 + 2) * 8 + f4];
        float4 w3 = Wl4[(4 * k4 + 3) * 8 + f4];
        float4 v0 = x4[k4];
        float4 v1 = x4[k4 + 32];
        a0x += v0.x * w0.x + v0.y * w1.x + v0.z * w2.x + v0.w * w3.x;
        a0y += v0.x * w0.y + v0.y * w1.y + v0.z * w2.y + v0.w * w3.y;
        a0z += v0.x * w0.z + v0.y * w1.z + v0.z * w2.z + v0.w * w3.z;
        a0w += v0.x * w0.w + v0.y * w1.w + v0.z * w2.w + v0.w * w3.w;
        a1x += v1.x * w0.x + v1.y * w1.x + v1.z * w2.x + v1.w * w3.x;
        a1y += v1.x * w0.y + v1.y * w1.y + v1.z * w2.y + v1.w * w3.y;
        a1z += v1.x * w0.z + v1.y * w1.z + v1.z * w2.z + v1.w * w3.z;
        a1w += v1.x * w0.w + v1.y * w1.w + v1.z * w2.w + v1.w * w3.w;
    }

    int r0 = 2 * g;
    float d0 = dinv[r0], d1 = dinv[r0 + 1];
    uint2* h1v = (uint2*)h1s;
    {
        unsigned p01 = (unsigned)__half_as_ushort(__float2half(d0 * a0x))
                     | ((unsigned)__half_as_ushort(__float2half(d0 * a0y)) << 16);
        unsigned p23 = (unsigned)__half_as_ushort(__float2half(d0 * a0z))
                     | ((unsigned)__half_as_ushort(__float2half(d0 * a0w)) << 16);
        h1v[(size_t)r0 * 8 + f4] = make_uint2(p01, p23);
    }
    {
        unsigned p01 = (unsigned)__half_as_ushort(__float2half(d1 * a1x))
                     | ((unsigned)__half_as_ushort(__float2half(d1 * a1y)) << 16);
        unsigned p23 = (unsigned)__half_as_ushort(__float2half(d1 * a1z))
                     | ((unsigned)__half_as_ushort(__float2half(d1 * a1w)) << 16);
        h1v[(size_t)(r0 + 1) * 8 + f4] = make_uint2(p01, p23);
    }
}

// ---------------- conv1: 8 nodes per wave (R13 structure, unchanged) ----------------
// lane = q*8 + o: slot q (0..7) owns node c = waveBase + q; o (0..7) owns feat quad [4o,4o+4).

__global__ __launch_bounds__(256) void k_conv1(const int* __restrict__ off, const int* __restrict__ end,
                                               const int* __restrict__ srt, const float* __restrict__ dinv,
                                               const unsigned* __restrict__ h1s,
                                               const float* __restrict__ W2, float* __restrict__ h2s4) {
    int t = threadIdx.x;
    if (blockIdx.x == 0 && t < 4) h2s4[(size_t)N_NODES * 4 + t] = 0.0f;  // zero row for k_conv2 masks
    int lane = t & 63, wid = t >> 6;
    int q = lane >> 3, o = lane & 7;
    int c = (blockIdx.x * 4 + wid) * 8 + q;   // grid = N/32 exactly -> c < N_NODES always

    int b = off[c], e = end[c];
    const char* h1b = (const char*)h1s;
    unsigned oo = (unsigned)(o << 3);
    // self-loop row: independent load, issue before the gather loop
    uint2 sv = *(const uint2*)(h1b + (((unsigned)c << 6) + oo));
    int last = (e > b) ? (e - 1) : b;         // safe clamp index (deg-0 slot reads srt[b], in-bounds)

    float a0a = 0.f, a1a = 0.f, a2a = 0.f, a3a = 0.f;
    float a0b = 0.f, a1b = 0.f, a2b = 0.f, a3b = 0.f;
    float a0c = 0.f, a1c = 0.f, a2c = 0.f, a3c = 0.f;
    float a0d = 0.f, a1d = 0.f, a2d = 0.f, a3d = 0.f;

    int p = b;
    while (__any(p < e)) {
        int i0 = min(p,     last);
        int i1 = min(p + 1, last);
        int i2 = min(p + 2, last);
        int i3 = min(p + 3, last);
        int r0 = srt[i0];
        int r1 = srt[i1];
        int r2 = srt[i2];
        int r3 = srt[i3];
        r0 = (p     < e) ? r0 : N_NODES;      // masked -> zero row
        r1 = (p + 1 < e) ? r1 : N_NODES;
        r2 = (p + 2 < e) ? r2 : N_NODES;
        r3 = (p + 3 < e) ? r3 : N_NODES;
        uint2 v0 = *(const uint2*)(h1b + (((unsigned)r0 << 6) + oo));
        uint2 v1 = *(const uint2*)(h1b + (((unsigned)r1 << 6) + oo));
        uint2 v2 = *(const uint2*)(h1b + (((unsigned)r2 << 6) + oo));
        uint2 v3 = *(const uint2*)(h1b + (((unsigned)r3 << 6) + oo));
        a0a += __low2float(*(const __half2*)&v0.x);  a1a += __high2float(*(const __half2*)&v0.x);
        a2a += __low2float(*(const __half2*)&v0.y);  a3a += __high2float(*(const __half2*)&v0.y);
        a0b += __low2float(*(const __half2*)&v1.x);  a1b += __high2float(*(const __half2*)&v1.x);
        a2b += __low2float(*(const __half2*)&v1.y);  a3b += __high2float(*(const __half2*)&v1.y);
        a0c += __low2float(*(const __half2*)&v2.x);  a1c += __high2float(*(const __half2*)&v2.x);
        a2c += __low2float(*(const __half2*)&v2.y);  a3c += __high2float(*(const __half2*)&v2.y);
        a0d += __low2float(*(const __half2*)&v3.x);  a1d += __high2float(*(const __half2*)&v3.x);
        a2d += __low2float(*(const __half2*)&v3.y);  a3d += __high2float(*(const __half2*)&v3.y);
        p += 4;
    }

    float di = dinv[c];
    float f0 = (a0a + a0b) + (a0c + a0d) + __low2float(*(const __half2*)&sv.x);
    float f1 = (a1a + a1b) + (a1c + a1d) + __high2float(*(const __half2*)&sv.x);
    float f2 = (a2a + a2b) + (a2c + a2d) + __low2float(*(const __half2*)&sv.y);
    float f3 = (a3a + a3b) + (a3c + a3d) + __high2float(*(const __half2*)&sv.y);

    float h0 = fast_tanh(di * f0);
    float h1 = fast_tanh(di * f1);
    float h2 = fast_tanh(di * f2);
    float h3 = fast_tanh(di * f3);

    // W2 rows for feats 4o..4o+3 (loaded post-loop to keep loop VGPR pressure low)
    const float* Wp = W2 + (o << 2) * 3;
    float p0 = h0 * Wp[0] + h1 * Wp[3] + h2 * Wp[6] + h3 * Wp[9];
    float p1 = h0 * Wp[1] + h1 * Wp[4] + h2 * Wp[7] + h3 * Wp[10];
    float p2 = h0 * Wp[2] + h1 * Wp[5] + h2 * Wp[8] + h3 * Wp[11];
#pragma unroll
    for (int m = 1; m <= 4; m <<= 1) {       // reduce over the 8 feat lanes (o), within each slot
        p0 += __shfl_xor(p0, m);
        p1 += __shfl_xor(p1, m);
        p2 += __shfl_xor(p2, m);
    }
    if (o < 4) {
        float vv = (o == 0) ? p0 : (o == 1) ? p1 : (o == 2) ? p2 : 0.0f;
        h2s4[(size_t)c * 4 + o] = (o < 3) ? di * vv : 0.0f;   // slot 3 = real 0
    }
}

// ---------------- conv2: 4 lanes per node, int4 srt loads, zero-row masking (R14) ----------------

__global__ __launch_bounds__(256) void k_conv2(const int* __restrict__ off, const int* __restrict__ end,
                                               const int* __restrict__ srt, const float* __restrict__ dinv,
                                               const float* __restrict__ h2s4, float* __restrict__ out) {
    int gt = blockIdx.x * 256 + threadIdx.x;
    int c = gt >> 2, j = gt & 3;
    if (c >= N_NODES) return;

    const float4* h2v = (const float4*)h2s4;
    int b = off[c], e = end[c];
    float4 sv = h2v[c];                      // self-loop term (w component = 0)
    float ax = (j == 0) ? sv.x : 0.0f;
    float ay = (j == 0) ? sv.y : 0.0f;
    float az = (j == 0) ? sv.z : 0.0f;

    int p = (b & ~3) + 4 * j;
    while (p < e) {
        int4 rs = *(const int4*)(srt + p);
        int r0 = (p     >= b && p     < e) ? rs.x : N_NODES;
        int r1 = (p + 1 >= b && p + 1 < e) ? rs.y : N_NODES;
        int r2 = (p + 2 >= b && p + 2 < e) ? rs.z : N_NODES;
        int r3 = (p + 3 >= b && p + 3 < e) ? rs.w : N_NODES;
        float4 v0 = h2v[r0];
        float4 v1 = h2v[r1];
        float4 v2 = h2v[r2];
        float4 v3 = h2v[r3];
        ax += (v0.x + v1.x) + (v2.x + v3.x);
        ay += (v0.y + v1.y) + (v2.y + v3.y);
        az += (v0.z + v1.z) + (v2.z + v3.z);
        p += 16;
    }
#pragma unroll
    for (int m = 1; m <= 2; m <<= 1) {       // reduce over the 4 quad lanes
        ax += __shfl_xor(ax, m);
        ay += __shfl_xor(ay, m);
        az += __shfl_xor(az, m);
    }

    float di = dinv[c];
    if (j < 3) {
        float a = (j == 0) ? ax : (j == 1) ? ay : az;
        out[(size_t)c * 3 + j] = di * a;     // 3 consecutive lanes -> coalesced
    }
}

// ---------------- launch ----------------

extern "C" void kernel_launch(void* const* d_in, const int* in_sizes, int n_in,
                              void* d_out, int out_size, void* d_ws, size_t ws_size,
                              hipStream_t stream) {
    const float* x   = (const float*)d_in[0];
    const int*   ei  = (const int*)d_in[1];  // [2, E] int32
    const float* W1  = (const float*)d_in[2];
    const float* W2  = (const float*)d_in[3];
    float*       out = (float*)d_out;

    const int* row = ei;
    const int* col = ei + N_EDGES;

    char* ws = (char*)d_ws;
    unsigned* bkt = (unsigned*)ws;
    int*      srt = (int*)ws;                 // alias (in-place after k_bucket)
    char*     p   = ws + 4ull * NBKT * CAP;
    int*      gcur = (int*)p;                 p += 4ull * ((NBKT + 63) & ~63);
    int*      off  = (int*)p;                 p += 4ull * N_NODES;
    int*      end  = (int*)p;                 p += 4ull * N_NODES;
    float*    dinv = (float*)p;               p += 4ull * N_NODES;
    unsigned* h1s  = (unsigned*)p;            p += 64ull * (N_NODES + 1);  // +1 zero row
    float*    h2s4 = (float*)p;               // N_NODES+1 rows (zero row for conv2 masks)

    const int B = 256;
    hipMemsetAsync(gcur, 0, 4ull * NBKT, stream);
    hipLaunchKernelGGL(k_part,   dim3(NBLK_E), dim3(512),  0, stream, row, col, gcur, bkt);
    hipLaunchKernelGGL(k_bucket, dim3(NBKT),   dim3(1024), 0, stream, bkt, gcur, off, end, dinv);
    hipLaunchKernelGGL(k_gemm1,  dim3((NGRP2 * 8 + B - 1) / B), dim3(B), 0, stream, x, W1, dinv, h1s);
    hipLaunchKernelGGL(k_conv1,  dim3(N_NODES / 32), dim3(B), 0, stream,
                       off, end, srt, dinv, h1s, W2, h2s4);
    hipLaunchKernelGGL(k_conv2,  dim3((4 * N_NODES + B - 1) / B), dim3(B), 0, stream,
                       off, end, srt, dinv, h2s4, out);
}

// Round 6
// 228.192 us; speedup vs baseline: 1.1226x; 1.1226x over previous
//
#include <hip/hip_runtime.h>
#include <hip/hip_fp16.h>

#define N_NODES 100000
#define N_EDGES 3200000
#define F_IN    128
#define F_HID   32

#define BSHIFT  7
#define BKSZ    128                               // nodes per bucket
#define NBKT    ((N_NODES + BKSZ - 1) / BKSZ)     // 782
#define CAP     5120                              // bucket capacity: mean 4092 + 8 sigma + 4-align pad (<=384)
#define CHUNK   4096                              // edges per partition block
#define NBLK_E  ((N_EDGES + CHUNK - 1) / CHUNK)   // 782
#define RBITS   17                                // row id bits (100000 < 2^17)
#define RMASK   0x1FFFF

// fast tanh: 1 - 2/(exp2(x*2/ln2)+1). v_exp_f32 + v_rcp_f32 are ~1ulp approx
// -> abs err ~1e-6, far under the fp16-storage error budget (absmax ~1e-3).
__device__ __forceinline__ float fast_tanh(float x) {
    float t = __builtin_amdgcn_exp2f(x * 2.88539008f);   // e^{2x}
    return 1.0f - 2.0f * __builtin_amdgcn_rcpf(t + 1.0f);
}

// ---------------- coarse partition (fixed-capacity buckets, relative cursors) ----------------
// gcur[] zeroed by hipMemsetAsync; holds per-bucket edge count after k_part.

__global__ __launch_bounds__(512) void k_part(const int* __restrict__ row, const int* __restrict__ col,
                                              int* __restrict__ gcur, unsigned* __restrict__ bkt) {
    __shared__ int hist[NBKT];
    __shared__ int lbase[NBKT];          // local (block) exclusive prefix
    __shared__ int gbase[NBKT];          // global destination base (absolute)
    __shared__ unsigned perm[CHUNK];     // 16 KB: packed words, bucket-major
    __shared__ unsigned short pb[CHUNK]; // 8 KB: bucket id per slot
    __shared__ int wt[8];
    int t = threadIdx.x;
    for (int i = t; i < NBKT; i += 512) hist[i] = 0;
    __syncthreads();

    int e0 = blockIdx.x * CHUNK;
    int n  = min(CHUNK, N_EDGES - e0);
    int r[8], c[8], rk[8];
#pragma unroll
    for (int k = 0; k < 8; k++) {
        int idx = t + k * 512;
        if (idx < n) {
            r[k]  = row[e0 + idx];
            c[k]  = col[e0 + idx];
            rk[k] = atomicAdd(&hist[c[k] >> BSHIFT], 1);   // local rank in bucket
        }
    }
    __syncthreads();

    // block scan: each thread owns 2 consecutive buckets
    {
        int b0 = t * 2;
        int s0 = (b0     < NBKT) ? hist[b0]     : 0;
        int s1 = (b0 + 1 < NBKT) ? hist[b0 + 1] : 0;
        int tsum = s0 + s1;
        int lane = t & 63, wid = t >> 6;
        int incl = tsum;
#pragma unroll
        for (int sh = 1; sh < 64; sh <<= 1) {
            int u = __shfl_up(incl, sh);
            if (lane >= sh) incl += u;
        }
        if (lane == 63) wt[wid] = incl;
        __syncthreads();
        int wpre = 0;
        for (int w = 0; w < wid; w++) wpre += wt[w];
        int excl = wpre + incl - tsum;
        if (b0     < NBKT) lbase[b0]     = excl;
        if (b0 + 1 < NBKT) lbase[b0 + 1] = excl + s0;
    }
    for (int i = t; i < NBKT; i += 512) {
        int h = hist[i];
        gbase[i] = i * CAP + (h ? atomicAdd(&gcur[i], h) : 0);
    }
    __syncthreads();

#pragma unroll
    for (int k = 0; k < 8; k++) {
        int idx = t + k * 512;
        if (idx < n) {
            int b   = c[k] >> BSHIFT;
            int pos = lbase[b] + rk[k];
            perm[pos] = (unsigned)r[k] | ((unsigned)(c[k] & (BKSZ - 1)) << RBITS);
            pb[pos]   = (unsigned short)b;
        }
    }
    __syncthreads();

    for (int i = t; i < n; i += 512) {
        int b = pb[i];
        bkt[gbase[b] + (i - lbase[b])] = perm[i];
    }
}

// ---------------- per-bucket fine sort, IN PLACE (LDS staging), + off/end/dinv ----------------
// R17: per-node ranges are padded to a multiple of 4 (pad entries = N_NODES -> zero-row
// gathers downstream). end[] now stores the PADDED end. Makes conv1/conv2 inner loops
// maskless with aligned int4 srt loads. Scan is over padded lengths (still <= CAP).

__global__ __launch_bounds__(1024) void k_bucket(unsigned* __restrict__ bkt,  // in: bkt, out: srt (aliased)
                                                 const int* __restrict__ gcur,
                                                 int* __restrict__ off, int* __restrict__ end,
                                                 float* __restrict__ dinv) {
    __shared__ unsigned stg[CAP];   // 20 KB staging
    __shared__ int cnt[BKSZ];
    __shared__ int cur[BKSZ];
    __shared__ int wtot[2];
    int t = threadIdx.x, b = blockIdx.x;
    int s = b * CAP, m = gcur[b];   // gcur holds the bucket count
    if (t < BKSZ) cnt[t] = 0;
    __syncthreads();
    for (int i = t; i < m; i += 1024) {
        unsigned x = bkt[s + i];
        stg[i] = x;
        atomicAdd(&cnt[x >> RBITS], 1);
    }
    __syncthreads();

    int lane = t & 63, wid = t >> 6;
    int v = 0, v4 = 0, incl = 0;
    if (t < BKSZ) {
        v  = cnt[t];
        v4 = (v + 3) & ~3;            // padded length
        incl = v4;
        #pragma unroll
        for (int sh = 1; sh < 64; sh <<= 1) {
            int u = __shfl_up(incl, sh);
            if (lane >= sh) incl += u;
        }
        if (lane == 63) wtot[wid] = incl;
    }
    __syncthreads();
    if (t < BKSZ) {
        int wpre = (wid == 1) ? wtot[0] : 0;
        int excl = wpre + incl - v4;
        int base = s + excl;          // 4-aligned: s = b*CAP (CAP%4==0), excl = sum of v4's
        cur[t] = base;
        int g = b * BKSZ + t;
        if (g < N_NODES) {
            off[g]  = base;
            end[g]  = base + v4;      // PADDED end
            dinv[g] = rsqrtf((float)(v + 1));   // +1 self-loop (real degree)
        }
        for (int j = v; j < v4; j++) bkt[base + j] = N_NODES;   // pad -> zero row id
    }
    __syncthreads();
    for (int i = t; i < m; i += 1024) {
        unsigned x = stg[i];
        int p = atomicAdd(&cur[x >> RBITS], 1);
        bkt[p] = x & RMASK;   // srt: row ids grouped by dest node
    }
}

// ---------------- h1s = fp16( dinv[r] * (x @ W1)[r] ), 1 row x 4 feats/thread ----------------
// R17: reverted to the known-good R13 structure (2-row/4-row register tiles both collapsed
// occupancy to <10% via compiler load-hoisting, VGPR 144-148 -> 55-65 us).
// Row N_NODES is an all-zero row (gather target for predicated-off edges in k_conv1).

__global__ __launch_bounds__(256) void k_gemm1(const float* __restrict__ x, const float* __restrict__ W1,
                                               const float* __restrict__ dinv, unsigned* __restrict__ h1s) {
    __shared__ float Wlds[F_IN * F_HID];  // 16 KB, [k][f]
    int t = threadIdx.x;
    for (int i = t; i < F_IN * F_HID; i += 256) Wlds[i] = W1[i];
    __syncthreads();

    int gid = blockIdx.x * 256 + t;   // gid = r*8 + f4 ; feats 4f4..4f4+3
    int r = gid >> 3, f4 = gid & 7;
    if (r > N_NODES) return;
    if (r == N_NODES) {               // zero row for masked gathers
        ((uint2*)h1s)[(size_t)r * 8 + f4] = make_uint2(0u, 0u);
        return;
    }

    const float4* x4  = (const float4*)(x + (size_t)r * F_IN);
    const float4* Wl4 = (const float4*)Wlds;   // [(k)*8 + f4]
    float ax = 0.f, ay = 0.f, az = 0.f, aw = 0.f;
#pragma unroll
    for (int k4 = 0; k4 < F_IN / 4; k4++) {
        float4 xv = x4[k4];
        float4 w0 = Wl4[(4 * k4 + 0) * 8 + f4];
        ax += xv.x * w0.x; ay += xv.x * w0.y; az += xv.x * w0.z; aw += xv.x * w0.w;
        float4 w1 = Wl4[(4 * k4 + 1) * 8 + f4];
        ax += xv.y * w1.x; ay += xv.y * w1.y; az += xv.y * w1.z; aw += xv.y * w1.w;
        float4 w2 = Wl4[(4 * k4 + 2) * 8 + f4];
        ax += xv.z * w2.x; ay += xv.z * w2.y; az += xv.z * w2.z; aw += xv.z * w2.w;
        float4 w3 = Wl4[(4 * k4 + 3) * 8 + f4];
        ax += xv.w * w3.x; ay += xv.w * w3.y; az += xv.w * w3.z; aw += xv.w * w3.w;
    }
    float di = dinv[r];
    unsigned p01 = (unsigned)__half_as_ushort(__float2half(di * ax))
                 | ((unsigned)__half_as_ushort(__float2half(di * ay)) << 16);
    unsigned p23 = (unsigned)__half_as_ushort(__float2half(di * az))
                 | ((unsigned)__half_as_ushort(__float2half(di * aw)) << 16);
    ((uint2*)h1s)[(size_t)r * 8 + f4] = make_uint2(p01, p23);
}

// ---------------- conv1 R17: 8 nodes/wave, maskless padded ranges, int4 srt loads ----------
// lane = q*8 + o: slot q (0..7) owns node c = waveBase + q; o (0..7) owns feat quad [4o,4o+4).
// Ranges [off,end) are 4-aligned/padded; pad ids = N_NODES (zero row). Inner loop: one
// predicated int4 srt load (exec-masked, no selects) + 4 gathers + 16 cvt-adds.

__global__ __launch_bounds__(256) void k_conv1(const int* __restrict__ off, const int* __restrict__ end,
                                               const int* __restrict__ srt, const float* __restrict__ dinv,
                                               const unsigned* __restrict__ h1s,
                                               const float* __restrict__ W2, float* __restrict__ h2s4) {
    int t = threadIdx.x;
    if (blockIdx.x == 0 && t < 4) h2s4[(size_t)N_NODES * 4 + t] = 0.0f;  // zero row for k_conv2
    int lane = t & 63, wid = t >> 6;
    int q = lane >> 3, o = lane & 7;
    int c = (blockIdx.x * 4 + wid) * 8 + q;   // grid = N/32 exactly -> c < N_NODES always

    int b = off[c], ep = end[c];              // padded range, b % 4 == 0
    const char* h1b = (const char*)h1s;
    unsigned oo = (unsigned)(o << 3);
    // self-loop row: independent load, issue before the gather loop
    uint2 sv = *(const uint2*)(h1b + (((unsigned)c << 6) + oo));

    float a0a = 0.f, a1a = 0.f, a2a = 0.f, a3a = 0.f;
    float a0b = 0.f, a1b = 0.f, a2b = 0.f, a3b = 0.f;
    float a0c = 0.f, a1c = 0.f, a2c = 0.f, a3c = 0.f;
    float a0d = 0.f, a1d = 0.f, a2d = 0.f, a3d = 0.f;

    int p = b;
    while (__any(p < ep)) {
        int r0 = N_NODES, r1 = N_NODES, r2 = N_NODES, r3 = N_NODES;
        if (p < ep) {                          // exec-masked aligned load; no per-edge selects
            int4 rs = *(const int4*)(srt + p);
            r0 = rs.x; r1 = rs.y; r2 = rs.z; r3 = rs.w;
        }
        uint2 v0 = *(const uint2*)(h1b + (((unsigned)r0 << 6) + oo));
        uint2 v1 = *(const uint2*)(h1b + (((unsigned)r1 << 6) + oo));
        uint2 v2 = *(const uint2*)(h1b + (((unsigned)r2 << 6) + oo));
        uint2 v3 = *(const uint2*)(h1b + (((unsigned)r3 << 6) + oo));
        a0a += __low2float(*(const __half2*)&v0.x);  a1a += __high2float(*(const __half2*)&v0.x);
        a2a += __low2float(*(const __half2*)&v0.y);  a3a += __high2float(*(const __half2*)&v0.y);
        a0b += __low2float(*(const __half2*)&v1.x);  a1b += __high2float(*(const __half2*)&v1.x);
        a2b += __low2float(*(const __half2*)&v1.y);  a3b += __high2float(*(const __half2*)&v1.y);
        a0c += __low2float(*(const __half2*)&v2.x);  a1c += __high2float(*(const __half2*)&v2.x);
        a2c += __low2float(*(const __half2*)&v2.y);  a3c += __high2float(*(const __half2*)&v2.y);
        a0d += __low2float(*(const __half2*)&v3.x);  a1d += __high2float(*(const __half2*)&v3.x);
        a2d += __low2float(*(const __half2*)&v3.y);  a3d += __high2float(*(const __half2*)&v3.y);
        p += 4;
    }

    float di = dinv[c];
    float f0 = (a0a + a0b) + (a0c + a0d) + __low2float(*(const __half2*)&sv.x);
    float f1 = (a1a + a1b) + (a1c + a1d) + __high2float(*(const __half2*)&sv.x);
    float f2 = (a2a + a2b) + (a2c + a2d) + __low2float(*(const __half2*)&sv.y);
    float f3 = (a3a + a3b) + (a3c + a3d) + __high2float(*(const __half2*)&sv.y);

    float h0 = fast_tanh(di * f0);
    float h1 = fast_tanh(di * f1);
    float h2 = fast_tanh(di * f2);
    float h3 = fast_tanh(di * f3);

    // W2 rows for feats 4o..4o+3 (loaded post-loop to keep loop VGPR pressure low)
    const float* Wp = W2 + (o << 2) * 3;
    float p0 = h0 * Wp[0] + h1 * Wp[3] + h2 * Wp[6] + h3 * Wp[9];
    float p1 = h0 * Wp[1] + h1 * Wp[4] + h2 * Wp[7] + h3 * Wp[10];
    float p2 = h0 * Wp[2] + h1 * Wp[5] + h2 * Wp[8] + h3 * Wp[11];
#pragma unroll
    for (int m = 1; m <= 4; m <<= 1) {       // reduce over the 8 feat lanes (o), within each slot
        p0 += __shfl_xor(p0, m);
        p1 += __shfl_xor(p1, m);
        p2 += __shfl_xor(p2, m);
    }
    if (o < 4) {
        float vv = (o == 0) ? p0 : (o == 1) ? p1 : (o == 2) ? p2 : 0.0f;
        h2s4[(size_t)c * 4 + o] = (o < 3) ? di * vv : 0.0f;   // slot 3 = real 0
    }
}

// ---------------- conv2 R17: 4 lanes/node, maskless padded ranges ----------------
// Quad j of node c walks p = b+4j, step 16, aligned int4 loads, NO range checks:
// pad ids gather the all-zero h2s4 row. Per-lane loop bound (divergence reconverges at end).

__global__ __launch_bounds__(256) void k_conv2(const int* __restrict__ off, const int* __restrict__ end,
                                               const int* __restrict__ srt, const float* __restrict__ dinv,
                                               const float* __restrict__ h2s4, float* __restrict__ out) {
    int gt = blockIdx.x * 256 + threadIdx.x;
    int c = gt >> 2, j = gt & 3;
    if (c >= N_NODES) return;

    const float4* h2v = (const float4*)h2s4;
    int b = off[c], ep = end[c];             // padded, b % 4 == 0
    float4 sv = h2v[c];                      // self-loop term (w component = 0)
    float ax = (j == 0) ? sv.x : 0.0f;
    float ay = (j == 0) ? sv.y : 0.0f;
    float az = (j == 0) ? sv.z : 0.0f;

    for (int p = b + 4 * j; p < ep; p += 16) {
        int4 rs = *(const int4*)(srt + p);
        float4 v0 = h2v[rs.x];
        float4 v1 = h2v[rs.y];
        float4 v2 = h2v[rs.z];
        float4 v3 = h2v[rs.w];
        ax += (v0.x + v1.x) + (v2.x + v3.x);
        ay += (v0.y + v1.y) + (v2.y + v3.y);
        az += (v0.z + v1.z) + (v2.z + v3.z);
    }
#pragma unroll
    for (int m = 1; m <= 2; m <<= 1) {       // reduce over the 4 quad lanes
        ax += __shfl_xor(ax, m);
        ay += __shfl_xor(ay, m);
        az += __shfl_xor(az, m);
    }

    float di = dinv[c];
    if (j < 3) {
        float a = (j == 0) ? ax : (j == 1) ? ay : az;
        out[(size_t)c * 3 + j] = di * a;     // 3 consecutive lanes -> coalesced
    }
}

// ---------------- launch ----------------

extern "C" void kernel_launch(void* const* d_in, const int* in_sizes, int n_in,
                              void* d_out, int out_size, void* d_ws, size_t ws_size,
                              hipStream_t stream) {
    const float* x   = (const float*)d_in[0];
    const int*   ei  = (const int*)d_in[1];  // [2, E] int32
    const float* W1  = (const float*)d_in[2];
    const float* W2  = (const float*)d_in[3];
    float*       out = (float*)d_out;

    const int* row = ei;
    const int* col = ei + N_EDGES;

    char* ws = (char*)d_ws;
    unsigned* bkt = (unsigned*)ws;
    int*      srt = (int*)ws;                 // alias (in-place after k_bucket)
    char*     p   = ws + 4ull * NBKT * CAP;
    int*      gcur = (int*)p;                 p += 4ull * ((NBKT + 63) & ~63);
    int*      off  = (int*)p;                 p += 4ull * N_NODES;
    int*      end  = (int*)p;                 p += 4ull * N_NODES;
    float*    dinv = (float*)p;               p += 4ull * N_NODES;
    unsigned* h1s  = (unsigned*)p;            p += 64ull * (N_NODES + 1);  // +1 zero row
    float*    h2s4 = (float*)p;               // N_NODES+1 rows (zero row for conv2 masks)

    const int B = 256;
    hipMemsetAsync(gcur, 0, 4ull * NBKT, stream);
    hipLaunchKernelGGL(k_part,   dim3(NBLK_E), dim3(512),  0, stream, row, col, gcur, bkt);
    hipLaunchKernelGGL(k_bucket, dim3(NBKT),   dim3(1024), 0, stream, bkt, gcur, off, end, dinv);
    hipLaunchKernelGGL(k_gemm1,  dim3(((N_NODES + 1) * 8 + B - 1) / B), dim3(B), 0, stream, x, W1, dinv, h1s);
    hipLaunchKernelGGL(k_conv1,  dim3(N_NODES / 32), dim3(B), 0, stream,
                       off, end, srt, dinv, h1s, W2, h2s4);
    hipLaunchKernelGGL(k_conv2,  dim3((4 * N_NODES + B - 1) / B), dim3(B), 0, stream,
                       off, end, srt, dinv, h2s4, out);
}